// Round 2
// baseline (411.615 us; speedup 1.0000x reference)
//
#include <hip/hip_runtime.h>

#define NB 4
#define NC 256
#define NN 4096
#define NQK 32

typedef short short8 __attribute__((ext_vector_type(8)));
typedef float f32x4 __attribute__((ext_vector_type(4)));

#define MFMA16(a, b, c) __builtin_amdgcn_mfma_f32_16x16x32_bf16((a), (b), (c), 0, 0, 0)

__device__ __forceinline__ unsigned short f2bf(float f) {
  unsigned int u = __builtin_bit_cast(unsigned int, f);
  u += 0x7fffu + ((u >> 16) & 1u);
  return (unsigned short)(u >> 16);
}

// ---------------- K0: weights fp32 -> bf16 ----------------
__global__ void k_prep(const float* __restrict__ wq, const float* __restrict__ wk,
                       const float* __restrict__ wv,
                       unsigned short* __restrict__ wqb, unsigned short* __restrict__ wkb,
                       unsigned short* __restrict__ wvb) {
  int i = blockIdx.x * 256 + threadIdx.x;          // grid = 256 blocks -> 65536
  if (i < NQK * NC) { wqb[i] = f2bf(wq[i]); wkb[i] = f2bf(wk[i]); }
  wvb[i] = f2bf(wv[i]);
}

// ---------------- K1: x (b,c,n) fp32 -> xT (b,n,c) bf16 ----------------
__global__ void k_tr(const float* __restrict__ x, unsigned short* __restrict__ xT) {
  __shared__ unsigned short lds[64][66];
  int b = blockIdx.z, c0 = blockIdx.y * 64, n0 = blockIdx.x * 64;
  int t = threadIdx.x;
  int nl = t & 63, cq = t >> 6;
  const float* xp = x + ((size_t)(b * NC + c0)) * NN + n0;
#pragma unroll
  for (int r = 0; r < 16; ++r) {
    int cl = r * 4 + cq;
    lds[cl][nl] = f2bf(xp[(size_t)cl * NN + nl]);
  }
  __syncthreads();
  unsigned short* xo = xT + ((size_t)(b * NN + n0)) * NC + c0;
#pragma unroll
  for (int r = 0; r < 16; ++r) {
    int n2 = r * 4 + cq;
    xo[(size_t)n2 * NC + nl] = lds[nl][n2];
  }
}

// ---------------- K2: QKV projection (MFMA) ----------------
// q[b][n][32], kT[b][n][32] (n-major), v[b][c][n] bf16
__global__ __launch_bounds__(256) void k_proj(
    const unsigned short* __restrict__ xT,
    const unsigned short* __restrict__ wqb, const unsigned short* __restrict__ wkb,
    const unsigned short* __restrict__ wvb,
    const float* __restrict__ bq, const float* __restrict__ bk,
    const float* __restrict__ bv,
    unsigned short* __restrict__ qb, unsigned short* __restrict__ kTb,
    unsigned short* __restrict__ vb) {
  __shared__ unsigned short ldsv[256][68];
  int b = blockIdx.y, n0 = blockIdx.x * 64;
  int t = threadIdx.x, w = t >> 6, l = t & 63, lm = l & 15, lk = l >> 4;
  f32x4 qa[2] = {}, ka[2] = {}, va[16] = {};
  const unsigned short* xrow = xT + ((size_t)(b * NN + n0 + w * 16 + lm)) * NC + lk * 8;
#pragma unroll
  for (int kk = 0; kk < 8; ++kk) {
    short8 a = *(const short8*)(xrow + kk * 32);
    const unsigned short* wqp = wqb + lm * NC + kk * 32 + lk * 8;
    const unsigned short* wkp = wkb + lm * NC + kk * 32 + lk * 8;
    qa[0] = MFMA16(a, *(const short8*)(wqp), qa[0]);
    qa[1] = MFMA16(a, *(const short8*)(wqp + 16 * NC), qa[1]);
    ka[0] = MFMA16(a, *(const short8*)(wkp), ka[0]);
    ka[1] = MFMA16(a, *(const short8*)(wkp + 16 * NC), ka[1]);
#pragma unroll
    for (int ct = 0; ct < 16; ++ct) {
      const unsigned short* wvp = wvb + (ct * 16 + lm) * NC + kk * 32 + lk * 8;
      va[ct] = MFMA16(a, *(const short8*)(wvp), va[ct]);
    }
  }
  // q / kT epilogue: D row = n-local = lk*4+r, col = o = f*16+lm
  int nrow = n0 + w * 16 + lk * 4;
#pragma unroll
  for (int f = 0; f < 2; ++f) {
    float bqv = bq[f * 16 + lm], bkv = bk[f * 16 + lm];
#pragma unroll
    for (int r = 0; r < 4; ++r) {
      size_t o = ((size_t)(b * NN + nrow + r)) * NQK + f * 16 + lm;
      qb[o] = f2bf(qa[f][r] + bqv);
      kTb[o] = f2bf(ka[f][r] + bkv);
    }
  }
  // v: transpose (n,c)->(c,n) through LDS, then coalesced rows
#pragma unroll
  for (int ct = 0; ct < 16; ++ct) {
    float bvv = bv[ct * 16 + lm];
#pragma unroll
    for (int r = 0; r < 4; ++r)
      ldsv[ct * 16 + lm][w * 16 + lk * 4 + r] = f2bf(va[ct][r] + bvv);
  }
  __syncthreads();
#pragma unroll
  for (int rep = 0; rep < 64; ++rep) {
    int c = rep * 4 + (t >> 6);
    int n = t & 63;
    vb[((size_t)(b * NC + c)) * NN + n0 + n] = ldsv[c][n];
  }
}

// ---------------- K3: fused energy/softmax/attention-write/PV ----------------
// wg: (b, 64-row i-tile), 8 waves.
// energy roles: wave -> (is = w&3: 16-row i-slice, jh = w>>2: 32-j half of 64-j chunk)
// PV roles:     wave -> (cg = w&3: 64-row c-quarter, ih = w>>2: 32-col i-half)
__global__ __launch_bounds__(512) void k_attn(
    const unsigned short* __restrict__ qb, const unsigned short* __restrict__ kTb,
    const unsigned short* __restrict__ vb, const float* __restrict__ x,
    const float* __restrict__ gamma, float* __restrict__ out,
    float* __restrict__ attn) {
  __shared__ unsigned short ldsv[256][72];  // V tile [c][64j], pad->72 (16B-aligned rows, <=2-way reads)
  __shared__ unsigned short ldsp[64][72];   // P tile [i][64j] bf16
  __shared__ float ldsd[64][2];             // rowsum partials
  int b = blockIdx.y, i0 = blockIdx.x * 64;
  int t = threadIdx.x, w = t >> 6, l = t & 63, lm = l & 15, lk = l >> 4;
  int is = w & 3, jh = w >> 2;
  int cg = w & 3, ih = w >> 2;
  const f32x4 z = {0.f, 0.f, 0.f, 0.f};

  short8 qa = *(const short8*)(qb + ((size_t)(b * NN + i0 + is * 16 + lm)) * NQK + lk * 8);
  const unsigned short* kbase = kTb + (size_t)b * NN * NQK + lk * 8;

  // ---- pass A: D[i] = sum_j exp(e[i][j]); each wave sums its j-half ----
  float ds0[4] = {0.f, 0.f, 0.f, 0.f};
  for (int j0 = jh * 2048; j0 < jh * 2048 + 2048; j0 += 32) {
    short8 kf0 = *(const short8*)(kbase + (size_t)(j0 + lm) * NQK);
    short8 kf1 = *(const short8*)(kbase + (size_t)(j0 + 16 + lm) * NQK);
    f32x4 e0 = MFMA16(qa, kf0, z);
    f32x4 e1 = MFMA16(qa, kf1, z);
#pragma unroll
    for (int r = 0; r < 4; ++r) ds0[r] += __expf(e0[r]) + __expf(e1[r]);
  }
#pragma unroll
  for (int m = 1; m < 16; m <<= 1)
#pragma unroll
    for (int r = 0; r < 4; ++r) ds0[r] += __shfl_xor(ds0[r], m);
  if (lm == 0) {
#pragma unroll
    for (int r = 0; r < 4; ++r) ldsd[is * 16 + lk * 4 + r][jh] = ds0[r];
  }
  __syncthreads();
  float dinv[4];
#pragma unroll
  for (int r = 0; r < 4; ++r) {
    int row = is * 16 + lk * 4 + r;
    dinv[r] = 1.0f / (ldsd[row][0] + ldsd[row][1]);
  }

  // ---- pass B ----
  f32x4 acc[4][2] = {};
  float g = gamma[0];
  float* attn_b = attn + (size_t)b * NN * NN;
  for (int j0 = 0; j0 < NN; j0 += 64) {
    __syncthreads();  // previous chunk's LDS fully consumed
    // stage V tile [256][64] -> ldsv
#pragma unroll
    for (int it = 0; it < 4; ++it) {
      int qid = it * 512 + t;
      int row = qid >> 3, part = qid & 7;
      *(short8*)(&ldsv[row][part * 8]) =
          *(const short8*)(vb + ((size_t)(b * NC + row)) * NN + j0 + part * 8);
    }
    // energy + softmax + attention write + P staging (disjoint per wave)
    int jb = j0 + jh * 32;
    short8 kf0 = *(const short8*)(kbase + (size_t)(jb + lm) * NQK);
    short8 kf1 = *(const short8*)(kbase + (size_t)(jb + 16 + lm) * NQK);
    f32x4 e0 = MFMA16(qa, kf0, z);
    f32x4 e1 = MFMA16(qa, kf1, z);
    int irow = i0 + is * 16 + lk * 4;
#pragma unroll
    for (int r = 0; r < 4; ++r) {
      float p0 = __expf(e0[r]) * dinv[r];
      float p1 = __expf(e1[r]) * dinv[r];
      __builtin_nontemporal_store(p0, &attn_b[(size_t)(irow + r) * NN + jb + lm]);
      __builtin_nontemporal_store(p1, &attn_b[(size_t)(irow + r) * NN + jb + 16 + lm]);
      ldsp[is * 16 + lk * 4 + r][jh * 32 + lm] = f2bf(p0);
      ldsp[is * 16 + lk * 4 + r][jh * 32 + 16 + lm] = f2bf(p1);
    }
    __syncthreads();  // ldsv + ldsp ready
    // PV: O[c][i] += V[c][j] * P^T[j][i]
#pragma unroll
    for (int kk = 0; kk < 2; ++kk) {
      short8 pf0 = *(const short8*)(&ldsp[ih * 32 + lm][kk * 32 + lk * 8]);
      short8 pf1 = *(const short8*)(&ldsp[ih * 32 + 16 + lm][kk * 32 + lk * 8]);
#pragma unroll
      for (int ct = 0; ct < 4; ++ct) {
        short8 af = *(const short8*)(&ldsv[cg * 64 + ct * 16 + lm][kk * 32 + lk * 8]);
        acc[ct][0] = MFMA16(af, pf0, acc[ct][0]);
        acc[ct][1] = MFMA16(af, pf1, acc[ct][1]);
      }
    }
  }
  // epilogue: out = gamma*O + x
#pragma unroll
  for (int ct = 0; ct < 4; ++ct)
#pragma unroll
    for (int pt = 0; pt < 2; ++pt)
#pragma unroll
      for (int r = 0; r < 4; ++r) {
        int c = cg * 64 + ct * 16 + lk * 4 + r;
        int i = i0 + ih * 32 + pt * 16 + lm;
        size_t idx = ((size_t)(b * NC + c)) * NN + i;
        out[idx] = g * acc[ct][pt][r] + x[idx];
      }
}

extern "C" void kernel_launch(void* const* d_in, const int* in_sizes, int n_in,
                              void* d_out, int out_size, void* d_ws, size_t ws_size,
                              hipStream_t stream) {
  (void)in_sizes; (void)n_in; (void)out_size; (void)ws_size;
  const float* x  = (const float*)d_in[0];
  const float* wq = (const float*)d_in[1];
  const float* bq = (const float*)d_in[2];
  const float* wk = (const float*)d_in[3];
  const float* bk = (const float*)d_in[4];
  const float* wv = (const float*)d_in[5];
  const float* bv = (const float*)d_in[6];
  const float* gamma = (const float*)d_in[7];
  float* out  = (float*)d_out;
  float* attn = out + (size_t)NB * NC * NN;

  char* ws = (char*)d_ws;
  unsigned short* xT  = (unsigned short*)(ws);               //  8,388,608 B
  unsigned short* qb  = (unsigned short*)(ws + 8388608);     //  1,048,576 B
  unsigned short* kTb = (unsigned short*)(ws + 9437184);     //  1,048,576 B
  unsigned short* vb  = (unsigned short*)(ws + 10485760);    //  8,388,608 B
  unsigned short* wqb = (unsigned short*)(ws + 18874368);    //     16,384 B
  unsigned short* wkb = (unsigned short*)(ws + 18890752);    //     16,384 B
  unsigned short* wvb = (unsigned short*)(ws + 18907136);    //    131,072 B

  k_prep<<<dim3(256), dim3(256), 0, stream>>>(wq, wk, wv, wqb, wkb, wvb);
  k_tr<<<dim3(64, 4, 4), dim3(256), 0, stream>>>(x, xT);
  k_proj<<<dim3(64, 4), dim3(256), 0, stream>>>(xT, wqb, wkb, wvb, bq, bk, bv,
                                                qb, kTb, vb);
  k_attn<<<dim3(64, 4), dim3(512), 0, stream>>>(qb, kTb, vb, x, gamma, out, attn);
}

// Round 5
// 395.984 us; speedup vs baseline: 1.0395x; 1.0395x over previous
//
#include <hip/hip_runtime.h>

#define NB 4
#define NC 256
#define NN 4096
#define NQK 32

typedef short short8 __attribute__((ext_vector_type(8)));
typedef float f32x4 __attribute__((ext_vector_type(4)));

#define MFMA16(a, b, c) __builtin_amdgcn_mfma_f32_16x16x32_bf16((a), (b), (c), 0, 0, 0)

#if __has_builtin(__builtin_amdgcn_exp2f)
#define EXP2(x) __builtin_amdgcn_exp2f(x)
#else
#define EXP2(x) __expf((x) * 0.6931471805599453f)
#endif

#define L2E 1.4426950408889634f

__device__ __forceinline__ unsigned short f2bf(float f) {
  unsigned int u = __builtin_bit_cast(unsigned int, f);
  u += 0x7fffu + ((u >> 16) & 1u);
  return (unsigned short)(u >> 16);
}
__device__ __forceinline__ float bf2f(unsigned short u) {
  unsigned int v = ((unsigned int)u) << 16;
  return __builtin_bit_cast(float, v);
}

// ---------------- K0: weights fp32 -> bf16 ----------------
__global__ void k_prep(const float* __restrict__ wq, const float* __restrict__ wk,
                       const float* __restrict__ wv,
                       unsigned short* __restrict__ wqb, unsigned short* __restrict__ wkb,
                       unsigned short* __restrict__ wvb) {
  int i = blockIdx.x * 256 + threadIdx.x;  // 65536 = NC*NC
  if (i < NQK * NC) { wqb[i] = f2bf(wq[i]); wkb[i] = f2bf(wk[i]); }
  wvb[i] = f2bf(wv[i]);
}

// ---------------- K1: QKV projection with fused x-transpose ----------------
// grid (128, 4): 32 n-rows per block, 256 threads (2 blocks/CU).
// wave w: n-slice s=w&1 (16 rows), channel-half h=w>>1 (h0: q,k,v[0..95]; h1: v[96..255])
// outputs: q[b][n][32] (pre-scaled by log2e), kT[b][n][32], v[b][c][n] bf16
__global__ __launch_bounds__(256) void k_proj(
    const float* __restrict__ x,
    const unsigned short* __restrict__ wqb, const unsigned short* __restrict__ wkb,
    const unsigned short* __restrict__ wvb,
    const float* __restrict__ bq, const float* __restrict__ bk,
    const float* __restrict__ bv,
    unsigned short* __restrict__ qb, unsigned short* __restrict__ kTb,
    unsigned short* __restrict__ vb) {
  __shared__ unsigned short ldsx[32][264];    // x^T tile [n][c], pad 256->264
  __shared__ unsigned short ldsvt[256][40];   // v tile [c][n], pad 32->40
  int b = blockIdx.y, n0 = blockIdx.x * 32;
  int t = threadIdx.x, w = t >> 6, l = t & 63, lm = l & 15, lk = l >> 4;
  // stage x[256c][32n] -> ldsx[n][c] (bf16)
  const float* xb = x + (size_t)b * NC * NN + n0;
#pragma unroll
  for (int p = 0; p < 8; ++p) {
    int c = p * 32 + (t >> 3);
    int n4 = (t & 7) * 4;
    f32x4 v4 = *(const f32x4*)(xb + (size_t)c * NN + n4);
#pragma unroll
    for (int u = 0; u < 4; ++u) ldsx[n4 + u][c] = f2bf(v4[u]);
  }
  __syncthreads();
  int s = w & 1, h = w >> 1;
  f32x4 qa[2] = {}, ka[2] = {}, va[10] = {};
  if (h == 0) {
#pragma unroll
    for (int kk = 0; kk < 8; ++kk) {
      short8 a = *(const short8*)(&ldsx[s * 16 + lm][kk * 32 + lk * 8]);
      const unsigned short* wqp = wqb + lm * NC + kk * 32 + lk * 8;
      const unsigned short* wkp = wkb + lm * NC + kk * 32 + lk * 8;
      qa[0] = MFMA16(a, *(const short8*)(wqp), qa[0]);
      qa[1] = MFMA16(a, *(const short8*)(wqp + 16 * NC), qa[1]);
      ka[0] = MFMA16(a, *(const short8*)(wkp), ka[0]);
      ka[1] = MFMA16(a, *(const short8*)(wkp + 16 * NC), ka[1]);
#pragma unroll
      for (int j = 0; j < 6; ++j) {
        const unsigned short* wvp = wvb + (size_t)(j * 16 + lm) * NC + kk * 32 + lk * 8;
        va[j] = MFMA16(a, *(const short8*)(wvp), va[j]);
      }
    }
  } else {
#pragma unroll
    for (int kk = 0; kk < 8; ++kk) {
      short8 a = *(const short8*)(&ldsx[s * 16 + lm][kk * 32 + lk * 8]);
#pragma unroll
      for (int j = 0; j < 10; ++j) {
        const unsigned short* wvp = wvb + (size_t)(96 + j * 16 + lm) * NC + kk * 32 + lk * 8;
        va[j] = MFMA16(a, *(const short8*)(wvp), va[j]);
      }
    }
  }
  // q / kT epilogue (h=0 waves): row = n0+s*16+lk*4+r, col = f*16+lm
  if (h == 0) {
    int nrow = n0 + s * 16 + lk * 4;
#pragma unroll
    for (int f = 0; f < 2; ++f) {
      float bqv = bq[f * 16 + lm], bkv = bk[f * 16 + lm];
#pragma unroll
      for (int r = 0; r < 4; ++r) {
        size_t o = ((size_t)(b * NN + nrow + r)) * NQK + f * 16 + lm;
        qb[o] = f2bf((qa[f][r] + bqv) * L2E);  // fold log2e for exp2 softmax
        kTb[o] = f2bf(ka[f][r] + bkv);
      }
    }
#pragma unroll
    for (int j = 0; j < 6; ++j) {
      float bvv = bv[j * 16 + lm];
#pragma unroll
      for (int r = 0; r < 4; ++r)
        ldsvt[j * 16 + lm][s * 16 + lk * 4 + r] = f2bf(va[j][r] + bvv);
    }
  } else {
#pragma unroll
    for (int j = 0; j < 10; ++j) {
      float bvv = bv[96 + j * 16 + lm];
#pragma unroll
      for (int r = 0; r < 4; ++r)
        ldsvt[96 + j * 16 + lm][s * 16 + lk * 4 + r] = f2bf(va[j][r] + bvv);
    }
  }
  __syncthreads();
  // cooperative coalesced v write: [256c][32n]
#pragma unroll
  for (int p = 0; p < 4; ++p) {
    int c = p * 64 + (t >> 2);
    int np = (t & 3) * 8;
    *(short8*)(vb + ((size_t)(b * NC + c)) * NN + n0 + np) =
        *(const short8*)(&ldsvt[c][np]);
  }
}

// ---------------- K2: fused energy/softmax/attention-write/PV ----------------
// grid 256 wgs, 512 threads. XCD-swizzled: id&7 -> XCD; b=(id>>1)&3 so each
// batch's V/K stay L2-resident on 2 XCDs.
// energy roles: wave -> (is=w&3: 16-row i-slice, jh=w>>2: 32-j half)
// PV roles:     wave -> (cg=w&3: 64-row c-quarter, ih=w>>2: 32-col i-half)
// Double-buffered ldsv/ldsp: ONE barrier per 64-j chunk.
__global__ __launch_bounds__(512) void k_attn(
    const unsigned short* __restrict__ qb, const unsigned short* __restrict__ kTb,
    const unsigned short* __restrict__ vb, const float* __restrict__ x,
    const float* __restrict__ gamma, float* __restrict__ out,
    float* __restrict__ attn) {
  __shared__ unsigned short ldsv[2][256][72];  // V tile [c][64j] (pad->72)
  __shared__ unsigned short ldsp[2][64][72];   // P tile [i][64j] bf16
  __shared__ float ldsd[64][2];                // rowsum partials
  int id = blockIdx.x;
  int b = (id >> 1) & 3;
  int i0 = (((id >> 3) << 1) | (id & 1)) * 64;
  int t = threadIdx.x, w = t >> 6, l = t & 63, lm = l & 15, lk = l >> 4;
  int is = w & 3, jh = w >> 2;
  int cg = w & 3, ih = w >> 2;
  const f32x4 z = {0.f, 0.f, 0.f, 0.f};

  short8 qa = *(const short8*)(qb + ((size_t)(b * NN + i0 + is * 16 + lm)) * NQK + lk * 8);
  const unsigned short* kbase = kTb + (size_t)b * NN * NQK + lk * 8;

  // ---- pass A: D[i] = sum_j exp2(e[i][j]) (e pre-scaled by log2e) ----
  float ds0[4] = {0.f, 0.f, 0.f, 0.f};
#pragma unroll 4
  for (int j0 = jh * 2048; j0 < jh * 2048 + 2048; j0 += 32) {
    short8 kf0 = *(const short8*)(kbase + (size_t)(j0 + lm) * NQK);
    short8 kf1 = *(const short8*)(kbase + (size_t)(j0 + 16 + lm) * NQK);
    f32x4 e0 = MFMA16(qa, kf0, z);
    f32x4 e1 = MFMA16(qa, kf1, z);
#pragma unroll
    for (int r = 0; r < 4; ++r) ds0[r] += EXP2(e0[r]) + EXP2(e1[r]);
  }
#pragma unroll
  for (int m = 1; m < 16; m <<= 1)
#pragma unroll
    for (int r = 0; r < 4; ++r) ds0[r] += __shfl_xor(ds0[r], m);
  if (lm == 0) {
#pragma unroll
    for (int r = 0; r < 4; ++r) ldsd[is * 16 + lk * 4 + r][jh] = ds0[r];
  }
  __syncthreads();
  float dinv[4];
#pragma unroll
  for (int r = 0; r < 4; ++r) {
    int row = is * 16 + lk * 4 + r;
    dinv[r] = 1.0f / (ldsd[row][0] + ldsd[row][1]);
  }

  // ---- pass B: produce(t) | barrier | consume(t); buffers alternate ----
  f32x4 acc[4][2] = {};
  float g = gamma[0];
  float* attn_b = attn + (size_t)b * NN * NN;
  const unsigned short* vbb = vb + (size_t)b * NC * NN;
  for (int tt = 0; tt < 64; ++tt) {
    int p = tt & 1;
    int j0 = tt * 64;
    // produce: stage V tile [256][64] -> ldsv[p]
#pragma unroll
    for (int it = 0; it < 4; ++it) {
      int qid = it * 512 + t;
      int row = qid >> 3, part = qid & 7;
      *(short8*)(&ldsv[p][row][part * 8]) =
          *(const short8*)(vbb + (size_t)row * NN + j0 + part * 8);
    }
    // produce: energy + softmax -> ldsp[p]
    int jb = j0 + jh * 32;
    short8 kf0 = *(const short8*)(kbase + (size_t)(jb + lm) * NQK);
    short8 kf1 = *(const short8*)(kbase + (size_t)(jb + 16 + lm) * NQK);
    f32x4 e0 = MFMA16(qa, kf0, z);
    f32x4 e1 = MFMA16(qa, kf1, z);
#pragma unroll
    for (int r = 0; r < 4; ++r) {
      float p0 = EXP2(e0[r]) * dinv[r];
      float p1 = EXP2(e1[r]) * dinv[r];
      int il = is * 16 + lk * 4 + r;
      ldsp[p][il][jh * 32 + lm] = f2bf(p0);
      ldsp[p][il][jh * 32 + 16 + lm] = f2bf(p1);
    }
    __syncthreads();
    // consume: cooperative vectorized attention write (1KB/instr)
#pragma unroll
    for (int q2 = 0; q2 < 2; ++q2) {
      int row = q2 * 32 + (t >> 4);
      int jl = (t & 15) * 4;
      f32x4 vo;
#pragma unroll
      for (int u = 0; u < 4; ++u) vo[u] = bf2f(ldsp[p][row][jl + u]);
      __builtin_nontemporal_store(vo, (f32x4*)(attn_b + (size_t)(i0 + row) * NN + j0 + jl));
    }
    // consume: PV  O[c][i] += V[c][j] * P^T[j][i]
#pragma unroll
    for (int kk = 0; kk < 2; ++kk) {
      short8 pf0 = *(const short8*)(&ldsp[p][ih * 32 + lm][kk * 32 + lk * 8]);
      short8 pf1 = *(const short8*)(&ldsp[p][ih * 32 + 16 + lm][kk * 32 + lk * 8]);
#pragma unroll
      for (int ct = 0; ct < 4; ++ct) {
        short8 af = *(const short8*)(&ldsv[p][cg * 64 + ct * 16 + lm][kk * 32 + lk * 8]);
        acc[ct][0] = MFMA16(af, pf0, acc[ct][0]);
        acc[ct][1] = MFMA16(af, pf1, acc[ct][1]);
      }
    }
  }
  // epilogue: out = gamma*O + x
#pragma unroll
  for (int ct = 0; ct < 4; ++ct)
#pragma unroll
    for (int pt = 0; pt < 2; ++pt)
#pragma unroll
      for (int r = 0; r < 4; ++r) {
        int c = cg * 64 + ct * 16 + lk * 4 + r;
        int i = i0 + ih * 32 + pt * 16 + lm;
        size_t idx = ((size_t)(b * NC + c)) * NN + i;
        out[idx] = g * acc[ct][pt][r] + x[idx];
      }
}

extern "C" void kernel_launch(void* const* d_in, const int* in_sizes, int n_in,
                              void* d_out, int out_size, void* d_ws, size_t ws_size,
                              hipStream_t stream) {
  (void)in_sizes; (void)n_in; (void)out_size; (void)ws_size;
  const float* x  = (const float*)d_in[0];
  const float* wq = (const float*)d_in[1];
  const float* bq = (const float*)d_in[2];
  const float* wk = (const float*)d_in[3];
  const float* bk = (const float*)d_in[4];
  const float* wv = (const float*)d_in[5];
  const float* bv = (const float*)d_in[6];
  const float* gamma = (const float*)d_in[7];
  float* out  = (float*)d_out;
  float* attn = out + (size_t)NB * NC * NN;

  char* ws = (char*)d_ws;
  unsigned short* qb  = (unsigned short*)(ws);               // 1,048,576 B
  unsigned short* kTb = (unsigned short*)(ws + 1048576);     // 1,048,576 B
  unsigned short* vb  = (unsigned short*)(ws + 2097152);     // 8,388,608 B
  unsigned short* wqb = (unsigned short*)(ws + 10485760);    //    16,384 B
  unsigned short* wkb = (unsigned short*)(ws + 10502144);    //    16,384 B
  unsigned short* wvb = (unsigned short*)(ws + 10518528);    //   131,072 B

  k_prep<<<dim3(256), dim3(256), 0, stream>>>(wq, wk, wv, wqb, wkb, wvb);
  k_proj<<<dim3(128, 4), dim3(256), 0, stream>>>(x, wqb, wkb, wvb, bq, bk, bv,
                                                 qb, kTb, vb);
  k_attn<<<dim3(256), dim3(512), 0, stream>>>(qb, kTb, vb, x, gamma, out, attn);
}

// Round 6
// 374.000 us; speedup vs baseline: 1.1006x; 1.0588x over previous
//
#include <hip/hip_runtime.h>

#define NB 4
#define NC 256
#define NN 4096
#define NQK 32

typedef short short4v __attribute__((ext_vector_type(4)));
typedef short short8 __attribute__((ext_vector_type(8)));
typedef float f32x4 __attribute__((ext_vector_type(4)));
typedef float f32x16 __attribute__((ext_vector_type(16)));

#define MFMA16(a, b, c) __builtin_amdgcn_mfma_f32_16x16x32_bf16((a), (b), (c), 0, 0, 0)
#define MFMA32(a, b, c) __builtin_amdgcn_mfma_f32_32x32x16_bf16((a), (b), (c), 0, 0, 0)

#if __has_builtin(__builtin_amdgcn_exp2f)
#define EXP2(x) __builtin_amdgcn_exp2f(x)
#else
#define EXP2(x) __expf((x) * 0.6931471805599453f)
#endif

#define L2E 1.4426950408889634f

__device__ __forceinline__ unsigned short f2bf(float f) {
  unsigned int u = __builtin_bit_cast(unsigned int, f);
  u += 0x7fffu + ((u >> 16) & 1u);
  return (unsigned short)(u >> 16);
}

// ---------------- K0: weights fp32 -> bf16 ----------------
__global__ void k_prep(const float* __restrict__ wq, const float* __restrict__ wk,
                       const float* __restrict__ wv,
                       unsigned short* __restrict__ wqb, unsigned short* __restrict__ wkb,
                       unsigned short* __restrict__ wvb) {
  int i = blockIdx.x * 256 + threadIdx.x;  // 65536 = NC*NC
  if (i < NQK * NC) { wqb[i] = f2bf(wq[i]); wkb[i] = f2bf(wk[i]); }
  wvb[i] = f2bf(wv[i]);
}

// ---------------- K1: QKV projection with fused x-transpose ----------------
// (unchanged from round 5)
__global__ __launch_bounds__(256) void k_proj(
    const float* __restrict__ x,
    const unsigned short* __restrict__ wqb, const unsigned short* __restrict__ wkb,
    const unsigned short* __restrict__ wvb,
    const float* __restrict__ bq, const float* __restrict__ bk,
    const float* __restrict__ bv,
    unsigned short* __restrict__ qb, unsigned short* __restrict__ kTb,
    unsigned short* __restrict__ vb) {
  __shared__ unsigned short ldsx[32][264];
  __shared__ unsigned short ldsvt[256][40];
  int b = blockIdx.y, n0 = blockIdx.x * 32;
  int t = threadIdx.x, w = t >> 6, l = t & 63, lm = l & 15, lk = l >> 4;
  const float* xb = x + (size_t)b * NC * NN + n0;
#pragma unroll
  for (int p = 0; p < 8; ++p) {
    int c = p * 32 + (t >> 3);
    int n4 = (t & 7) * 4;
    f32x4 v4 = *(const f32x4*)(xb + (size_t)c * NN + n4);
#pragma unroll
    for (int u = 0; u < 4; ++u) ldsx[n4 + u][c] = f2bf(v4[u]);
  }
  __syncthreads();
  int s = w & 1, h = w >> 1;
  f32x4 qa[2] = {}, ka[2] = {}, va[10] = {};
  if (h == 0) {
#pragma unroll
    for (int kk = 0; kk < 8; ++kk) {
      short8 a = *(const short8*)(&ldsx[s * 16 + lm][kk * 32 + lk * 8]);
      const unsigned short* wqp = wqb + lm * NC + kk * 32 + lk * 8;
      const unsigned short* wkp = wkb + lm * NC + kk * 32 + lk * 8;
      qa[0] = MFMA16(a, *(const short8*)(wqp), qa[0]);
      qa[1] = MFMA16(a, *(const short8*)(wqp + 16 * NC), qa[1]);
      ka[0] = MFMA16(a, *(const short8*)(wkp), ka[0]);
      ka[1] = MFMA16(a, *(const short8*)(wkp + 16 * NC), ka[1]);
#pragma unroll
      for (int j = 0; j < 6; ++j) {
        const unsigned short* wvp = wvb + (size_t)(j * 16 + lm) * NC + kk * 32 + lk * 8;
        va[j] = MFMA16(a, *(const short8*)(wvp), va[j]);
      }
    }
  } else {
#pragma unroll
    for (int kk = 0; kk < 8; ++kk) {
      short8 a = *(const short8*)(&ldsx[s * 16 + lm][kk * 32 + lk * 8]);
#pragma unroll
      for (int j = 0; j < 10; ++j) {
        const unsigned short* wvp = wvb + (size_t)(96 + j * 16 + lm) * NC + kk * 32 + lk * 8;
        va[j] = MFMA16(a, *(const short8*)(wvp), va[j]);
      }
    }
  }
  if (h == 0) {
    int nrow = n0 + s * 16 + lk * 4;
#pragma unroll
    for (int f = 0; f < 2; ++f) {
      float bqv = bq[f * 16 + lm], bkv = bk[f * 16 + lm];
#pragma unroll
      for (int r = 0; r < 4; ++r) {
        size_t o = ((size_t)(b * NN + nrow + r)) * NQK + f * 16 + lm;
        qb[o] = f2bf((qa[f][r] + bqv) * L2E);  // fold log2e for exp2 softmax
        kTb[o] = f2bf(ka[f][r] + bkv);
      }
    }
#pragma unroll
    for (int j = 0; j < 6; ++j) {
      float bvv = bv[j * 16 + lm];
#pragma unroll
      for (int r = 0; r < 4; ++r)
        ldsvt[j * 16 + lm][s * 16 + lk * 4 + r] = f2bf(va[j][r] + bvv);
    }
  } else {
#pragma unroll
    for (int j = 0; j < 10; ++j) {
      float bvv = bv[96 + j * 16 + lm];
#pragma unroll
      for (int r = 0; r < 4; ++r)
        ldsvt[96 + j * 16 + lm][s * 16 + lk * 4 + r] = f2bf(va[j][r] + bvv);
    }
  }
  __syncthreads();
#pragma unroll
  for (int p = 0; p < 4; ++p) {
    int c = p * 64 + (t >> 2);
    int np = (t & 3) * 8;
    *(short8*)(vb + ((size_t)(b * NC + c)) * NN + n0 + np) =
        *(const short8*)(&ldsvt[c][np]);
  }
}

// ---------------- K2: fused energy/softmax/attention-write/PV ----------------
// grid 256 wgs (XCD-swizzled), 512 threads, 1 wg/CU.
// Swapped energy MFMA: e = mfma(K, Q) -> lane holds (i = lm fixed, j = lk*4+r
// consecutive) => reg-direct f32x4 attn stores + ds_write_b64 P-writes +
// scalar dinv. PV: 32x32x16 MFMA, wave w owns c-slice [w*32, w*32+32).
// LDS: pitch 128B rows, XOR slot-swizzle (byte ^= (row&7)<<4) => conflict-free
// b128. ldsv single-buffered (2 barriers/chunk), ldsp double-buffered,
// V reg-staged (async: next chunk's loads issue between barriers).
__global__ __launch_bounds__(512) void k_attn(
    const unsigned short* __restrict__ qb, const unsigned short* __restrict__ kTb,
    const unsigned short* __restrict__ vb, const float* __restrict__ x,
    const float* __restrict__ gamma, float* __restrict__ out,
    float* __restrict__ attn) {
  __shared__ unsigned short ldsv[256 * 64];     // 32 KB  V tile [c][64j]
  __shared__ unsigned short ldsp[2][64 * 64];   // 16 KB  P tile [i][64j]
  __shared__ float ldsd[64][8];                 // rowsum partials
  int id = blockIdx.x;
  int b = (id >> 1) & 3;                         // id&7 -> XCD; batch per XCD-pair
  int i0 = (((id >> 3) << 1) | (id & 1)) * 64;
  int t = threadIdx.x, w = t >> 6, l = t & 63, lm = l & 15, lk = l >> 4;
  const f32x4 z = {0.f, 0.f, 0.f, 0.f};

  // Q fragments for all 4 i-slices of this wg's 64-row tile
  const unsigned short* qbb = qb + ((size_t)(b * NN + i0 + lm)) * NQK + lk * 8;
  short8 qa0 = *(const short8*)(qbb);
  short8 qa1 = *(const short8*)(qbb + 16 * NQK);
  short8 qa2 = *(const short8*)(qbb + 32 * NQK);
  short8 qa3 = *(const short8*)(qbb + 48 * NQK);
  const unsigned short* kbase = kTb + (size_t)b * NN * NQK + lk * 8;

  // ---- pass A: rowsums. wave w covers j in [w*512, (w+1)*512) for all 64 i.
  float s0 = 0.f, s1 = 0.f, s2 = 0.f, s3 = 0.f;
  for (int j0 = w * 512; j0 < w * 512 + 512; j0 += 16) {
    short8 kf = *(const short8*)(kbase + (size_t)(j0 + lm) * NQK);
    f32x4 e0 = MFMA16(kf, qa0, z);
    f32x4 e1 = MFMA16(kf, qa1, z);
    f32x4 e2 = MFMA16(kf, qa2, z);
    f32x4 e3 = MFMA16(kf, qa3, z);
#pragma unroll
    for (int r = 0; r < 4; ++r) {
      s0 += EXP2(e0[r]); s1 += EXP2(e1[r]);
      s2 += EXP2(e2[r]); s3 += EXP2(e3[r]);
    }
  }
  // sum over j within wave: reduce across lk groups (lanes with same lm)
  s0 += __shfl_xor(s0, 16); s0 += __shfl_xor(s0, 32);
  s1 += __shfl_xor(s1, 16); s1 += __shfl_xor(s1, 32);
  s2 += __shfl_xor(s2, 16); s2 += __shfl_xor(s2, 32);
  s3 += __shfl_xor(s3, 16); s3 += __shfl_xor(s3, 32);
  if (lk == 0) {
    ldsd[lm][w] = s0;       ldsd[16 + lm][w] = s1;
    ldsd[32 + lm][w] = s2;  ldsd[48 + lm][w] = s3;
  }
  __syncthreads();

  // ---- roles for pass B ----
  int is = w & 3, jh = w >> 2;   // energy: i-slice, j-half
  int cg = w;                    // PV: 32-row c-slice
  // energy Q frag (static select; runtime-indexed arrays go to scratch)
  short8 qe = (is == 0) ? qa0 : (is == 1) ? qa1 : (is == 2) ? qa2 : qa3;
  // dinv for this lane's i-row (i = is*16 + lm); broadcast reads
  int prow = is * 16 + lm;
  f32x4 dA = *(const f32x4*)(&ldsd[prow][0]);
  f32x4 dB = *(const f32x4*)(&ldsd[prow][4]);
  float dinv = 1.0f / (dA[0] + dA[1] + dA[2] + dA[3] + dB[0] + dB[1] + dB[2] + dB[3]);

  // per-lane precomputed addresses
  float g = gamma[0];
  float* attn_b = attn + (size_t)b * NN * NN;
  float* aptr = attn_b + (size_t)(i0 + prow) * NN + jh * 32 + lk * 4;
  const unsigned short* vbb = vb + (size_t)b * NC * NN;
  int vrow = t >> 3, vcol = t & 7;                     // V staging: +it*64 rows
  int vx = (vcol * 16) ^ ((vrow & 7) << 4);            // swizzled in-row byte
  char* vbase = (char*)ldsv;
  int pc0 = (jh * 64 + lk * 8) ^ ((prow & 7) << 4);    // P-write bytes (e0)
  int pc1 = (jh * 64 + lk * 8 + 32) ^ ((prow & 7) << 4);
  int rowa = cg * 32 + (l & 31);                       // PV af row (c)
  int xa = (rowa & 7) << 4;
  int xp = ((l & 31) & 7) << 4;                        // pf xor (same both ih)
  int chalf = (l >> 5) * 16;                           // k-half byte offset
  int rp0 = (l & 31) * 128, rp1 = (32 + (l & 31)) * 128;

  // V prologue: chunk 0 into registers
  short8 vr0 = *(const short8*)(vbb + (size_t)(vrow) * NN + vcol * 8);
  short8 vr1 = *(const short8*)(vbb + (size_t)(64 + vrow) * NN + vcol * 8);
  short8 vr2 = *(const short8*)(vbb + (size_t)(128 + vrow) * NN + vcol * 8);
  short8 vr3 = *(const short8*)(vbb + (size_t)(192 + vrow) * NN + vcol * 8);

  f32x16 acc0 = {}, acc1 = {};
  for (int tt = 0; tt < 64; ++tt) {
    int p = tt & 1;
    int j0 = tt * 64;
    int jb = j0 + jh * 32;
    // ---- energy + softmax + attn store + P write ----
    short8 kf0 = *(const short8*)(kbase + (size_t)(jb + lm) * NQK);
    short8 kf1 = *(const short8*)(kbase + (size_t)(jb + 16 + lm) * NQK);
    f32x4 e0 = MFMA16(kf0, qe, z);
    f32x4 e1 = MFMA16(kf1, qe, z);
    f32x4 p0, p1;
#pragma unroll
    for (int r = 0; r < 4; ++r) {
      p0[r] = EXP2(e0[r]) * dinv;
      p1[r] = EXP2(e1[r]) * dinv;
    }
    __builtin_nontemporal_store(p0, (f32x4*)(aptr + j0));
    __builtin_nontemporal_store(p1, (f32x4*)(aptr + j0 + 16));
    short4v pb0, pb1;
#pragma unroll
    for (int r = 0; r < 4; ++r) {
      pb0[r] = (short)f2bf(p0[r]);
      pb1[r] = (short)f2bf(p1[r]);
    }
    char* pb = (char*)(&ldsp[p][0]) + prow * 128;
    *(short4v*)(pb + pc0) = pb0;
    *(short4v*)(pb + pc1) = pb1;
    __syncthreads();  // bar1: PV(tt-1) done; ldsp[p] complete
    // ---- V stage (chunk tt) + issue next chunk's loads ----
    *(short8*)(vbase + (vrow) * 128 + vx) = vr0;
    *(short8*)(vbase + (64 + vrow) * 128 + vx) = vr1;
    *(short8*)(vbase + (128 + vrow) * 128 + vx) = vr2;
    *(short8*)(vbase + (192 + vrow) * 128 + vx) = vr3;
    {
      size_t jn = (size_t)(((tt + 1) & 63) * 64);
      vr0 = *(const short8*)(vbb + (size_t)(vrow) * NN + jn + vcol * 8);
      vr1 = *(const short8*)(vbb + (size_t)(64 + vrow) * NN + jn + vcol * 8);
      vr2 = *(const short8*)(vbb + (size_t)(128 + vrow) * NN + jn + vcol * 8);
      vr3 = *(const short8*)(vbb + (size_t)(192 + vrow) * NN + jn + vcol * 8);
    }
    __syncthreads();  // bar2: ldsv ready
    // ---- PV: acc[c-slice][64 i] += V * P^T ----
    const char* pvp = (const char*)(&ldsp[p][0]);
    const char* abase = vbase + rowa * 128;
    __builtin_amdgcn_s_setprio(1);
#pragma unroll
    for (int kk = 0; kk < 4; ++kk) {
      int cb = kk * 32 + chalf;
      short8 af = *(const short8*)(abase + (cb ^ xa));
      short8 pf0 = *(const short8*)(pvp + rp0 + (cb ^ xp));
      short8 pf1 = *(const short8*)(pvp + rp1 + (cb ^ xp));
      acc0 = MFMA32(af, pf0, acc0);
      acc1 = MFMA32(af, pf1, acc1);
    }
    __builtin_amdgcn_s_setprio(0);
  }

  // ---- epilogue: out = gamma*O + x ----
  // D mapping (32x32): col(i) = lane&31, row(c) = (reg&3) + 8*(reg>>2) + 4*(lane>>5)
  int ieg0 = i0 + (l & 31), ieg1 = i0 + 32 + (l & 31);
  int crb = cg * 32 + 4 * (l >> 5);
#pragma unroll
  for (int reg = 0; reg < 16; ++reg) {
    int c = crb + (reg & 3) + 8 * (reg >> 2);
    size_t o0 = ((size_t)(b * NC + c)) * NN + ieg0;
    size_t o1 = ((size_t)(b * NC + c)) * NN + ieg1;
    out[o0] = g * acc0[reg] + x[o0];
    out[o1] = g * acc1[reg] + x[o1];
  }
}

extern "C" void kernel_launch(void* const* d_in, const int* in_sizes, int n_in,
                              void* d_out, int out_size, void* d_ws, size_t ws_size,
                              hipStream_t stream) {
  (void)in_sizes; (void)n_in; (void)out_size; (void)ws_size;
  const float* x  = (const float*)d_in[0];
  const float* wq = (const float*)d_in[1];
  const float* bq = (const float*)d_in[2];
  const float* wk = (const float*)d_in[3];
  const float* bk = (const float*)d_in[4];
  const float* wv = (const float*)d_in[5];
  const float* bv = (const float*)d_in[6];
  const float* gamma = (const float*)d_in[7];
  float* out  = (float*)d_out;
  float* attn = out + (size_t)NB * NC * NN;

  char* ws = (char*)d_ws;
  unsigned short* qb  = (unsigned short*)(ws);               // 1,048,576 B
  unsigned short* kTb = (unsigned short*)(ws + 1048576);     // 1,048,576 B
  unsigned short* vb  = (unsigned short*)(ws + 2097152);     // 8,388,608 B
  unsigned short* wqb = (unsigned short*)(ws + 10485760);    //    16,384 B
  unsigned short* wkb = (unsigned short*)(ws + 10502144);    //    16,384 B
  unsigned short* wvb = (unsigned short*)(ws + 10518528);    //   131,072 B

  k_prep<<<dim3(256), dim3(256), 0, stream>>>(wq, wk, wv, wqb, wkb, wvb);
  k_proj<<<dim3(128, 4), dim3(256), 0, stream>>>(x, wqb, wkb, wvb, bq, bk, bv,
                                                 qb, kTb, vb);
  k_attn<<<dim3(256), dim3(512), 0, stream>>>(qb, kTb, vb, x, gamma, out, attn);
}

// Round 8
// 370.315 us; speedup vs baseline: 1.1115x; 1.0100x over previous
//
#include <hip/hip_runtime.h>

#define NB 4
#define NC 256
#define NN 4096
#define NQK 32

typedef short short4v __attribute__((ext_vector_type(4)));
typedef short short8 __attribute__((ext_vector_type(8)));
typedef float f32x4 __attribute__((ext_vector_type(4)));
typedef float f32x16 __attribute__((ext_vector_type(16)));

#define MFMA16(a, b, c) __builtin_amdgcn_mfma_f32_16x16x32_bf16((a), (b), (c), 0, 0, 0)
#define MFMA32(a, b, c) __builtin_amdgcn_mfma_f32_32x32x16_bf16((a), (b), (c), 0, 0, 0)

#if __has_builtin(__builtin_amdgcn_exp2f)
#define EXP2(x) __builtin_amdgcn_exp2f(x)
#else
#define EXP2(x) __expf((x) * 0.6931471805599453f)
#endif

#define L2E 1.4426950408889634f

__device__ __forceinline__ unsigned short f2bf(float f) {
  unsigned int u = __builtin_bit_cast(unsigned int, f);
  u += 0x7fffu + ((u >> 16) & 1u);
  return (unsigned short)(u >> 16);
}

// ---------------- K0: weights fp32 -> bf16 ----------------
__global__ void k_prep(const float* __restrict__ wq, const float* __restrict__ wk,
                       const float* __restrict__ wv,
                       unsigned short* __restrict__ wqb, unsigned short* __restrict__ wkb,
                       unsigned short* __restrict__ wvb) {
  int i = blockIdx.x * 256 + threadIdx.x;  // 65536 = NC*NC
  if (i < NQK * NC) { wqb[i] = f2bf(wq[i]); wkb[i] = f2bf(wk[i]); }
  wvb[i] = f2bf(wv[i]);
}

// ---------------- K1: QKV projection with fused x-transpose ----------------
// (unchanged from round 6)
__global__ __launch_bounds__(256) void k_proj(
    const float* __restrict__ x,
    const unsigned short* __restrict__ wqb, const unsigned short* __restrict__ wkb,
    const unsigned short* __restrict__ wvb,
    const float* __restrict__ bq, const float* __restrict__ bk,
    const float* __restrict__ bv,
    unsigned short* __restrict__ qb, unsigned short* __restrict__ kTb,
    unsigned short* __restrict__ vb) {
  __shared__ unsigned short ldsx[32][264];
  __shared__ unsigned short ldsvt[256][40];
  int b = blockIdx.y, n0 = blockIdx.x * 32;
  int t = threadIdx.x, w = t >> 6, l = t & 63, lm = l & 15, lk = l >> 4;
  const float* xb = x + (size_t)b * NC * NN + n0;
#pragma unroll
  for (int p = 0; p < 8; ++p) {
    int c = p * 32 + (t >> 3);
    int n4 = (t & 7) * 4;
    f32x4 v4 = *(const f32x4*)(xb + (size_t)c * NN + n4);
#pragma unroll
    for (int u = 0; u < 4; ++u) ldsx[n4 + u][c] = f2bf(v4[u]);
  }
  __syncthreads();
  int s = w & 1, h = w >> 1;
  f32x4 qa[2] = {}, ka[2] = {}, va[10] = {};
  if (h == 0) {
#pragma unroll
    for (int kk = 0; kk < 8; ++kk) {
      short8 a = *(const short8*)(&ldsx[s * 16 + lm][kk * 32 + lk * 8]);
      const unsigned short* wqp = wqb + lm * NC + kk * 32 + lk * 8;
      const unsigned short* wkp = wkb + lm * NC + kk * 32 + lk * 8;
      qa[0] = MFMA16(a, *(const short8*)(wqp), qa[0]);
      qa[1] = MFMA16(a, *(const short8*)(wqp + 16 * NC), qa[1]);
      ka[0] = MFMA16(a, *(const short8*)(wkp), ka[0]);
      ka[1] = MFMA16(a, *(const short8*)(wkp + 16 * NC), ka[1]);
#pragma unroll
      for (int j = 0; j < 6; ++j) {
        const unsigned short* wvp = wvb + (size_t)(j * 16 + lm) * NC + kk * 32 + lk * 8;
        va[j] = MFMA16(a, *(const short8*)(wvp), va[j]);
      }
    }
  } else {
#pragma unroll
    for (int kk = 0; kk < 8; ++kk) {
      short8 a = *(const short8*)(&ldsx[s * 16 + lm][kk * 32 + lk * 8]);
#pragma unroll
      for (int j = 0; j < 10; ++j) {
        const unsigned short* wvp = wvb + (size_t)(96 + j * 16 + lm) * NC + kk * 32 + lk * 8;
        va[j] = MFMA16(a, *(const short8*)(wvp), va[j]);
      }
    }
  }
  if (h == 0) {
    int nrow = n0 + s * 16 + lk * 4;
#pragma unroll
    for (int f = 0; f < 2; ++f) {
      float bqv = bq[f * 16 + lm], bkv = bk[f * 16 + lm];
#pragma unroll
      for (int r = 0; r < 4; ++r) {
        size_t o = ((size_t)(b * NN + nrow + r)) * NQK + f * 16 + lm;
        qb[o] = f2bf((qa[f][r] + bqv) * L2E);  // fold log2e for exp2 softmax
        kTb[o] = f2bf(ka[f][r] + bkv);
      }
    }
#pragma unroll
    for (int j = 0; j < 6; ++j) {
      float bvv = bv[j * 16 + lm];
#pragma unroll
      for (int r = 0; r < 4; ++r)
        ldsvt[j * 16 + lm][s * 16 + lk * 4 + r] = f2bf(va[j][r] + bvv);
    }
  } else {
#pragma unroll
    for (int j = 0; j < 10; ++j) {
      float bvv = bv[96 + j * 16 + lm];
#pragma unroll
      for (int r = 0; r < 4; ++r)
        ldsvt[96 + j * 16 + lm][s * 16 + lk * 4 + r] = f2bf(va[j][r] + bvv);
    }
  }
  __syncthreads();
#pragma unroll
  for (int p = 0; p < 4; ++p) {
    int c = p * 64 + (t >> 2);
    int np = (t & 3) * 8;
    *(short8*)(vb + ((size_t)(b * NC + c)) * NN + n0 + np) =
        *(const short8*)(&ldsvt[c][np]);
  }
}

// ---------------- K2: fused energy/softmax/attention-write/PV ----------------
// grid 512 wgs (2 wg/CU), 256 threads (4 waves), 32-row i-tile.
// XCD map: xcd=id&7, b=xcd>>1 (batch pinned to an XCD pair), tile=(id>>3)*2|(xcd&1).
// energy: wave -> (is=w&1: 16-row i-slice, jh=w>>1: 32-j half); swapped MFMA
//   (mfma(K,Q)) -> lane = (i=lm, 4 consecutive j) -> reg-direct f32x4 NT stores.
// PV: wave w owns c-slice [w*64, w*64+64), 32x32x16 MFMA, 2 acc chains.
// LDS: ldsv [256c][64j] 128B pitch, CONTENT-swizzled: global V loaded from
//   pre-swizzled source addr (col16 ^ (row&7)<<4), written LINEAR (0 write
//   conflicts), read swizzled in PV. ldsp double-buffered, XOR-swizzled.
__global__ __launch_bounds__(256, 2) void k_attn(
    const unsigned short* __restrict__ qb, const unsigned short* __restrict__ kTb,
    const unsigned short* __restrict__ vb, const float* __restrict__ x,
    const float* __restrict__ gamma, float* __restrict__ out,
    float* __restrict__ attn) {
  __shared__ unsigned short ldsv[256 * 64];    // 32 KB  V tile [c][64j]
  __shared__ unsigned short ldsp[2][32 * 64];  // 2 x 4 KB  P tile [32 i][64 j]
  __shared__ float ldsd[32][4];                // rowsum partials
  int id = blockIdx.x;
  int xcd = id & 7;
  int b = xcd >> 1;
  int i0 = (((id >> 3) << 1) | (xcd & 1)) * 32;
  int t = threadIdx.x, w = t >> 6, l = t & 63, lm = l & 15, lk = l >> 4;
  const f32x4 z = {0.f, 0.f, 0.f, 0.f};

  // Q fragments: rows i0+lm (qa0), i0+16+lm (qa1)
  const unsigned short* qbb = qb + ((size_t)(b * NN + i0 + lm)) * NQK + lk * 8;
  short8 qa0 = *(const short8*)(qbb);
  short8 qa1 = *(const short8*)(qbb + 16 * NQK);
  const unsigned short* kbase = kTb + (size_t)b * NN * NQK + lk * 8;

  // ---- pass A: rowsums; wave w covers j in [w*1024, (w+1)*1024) ----
  float s0 = 0.f, s1 = 0.f;
  for (int j0 = w * 1024; j0 < w * 1024 + 1024; j0 += 16) {
    short8 kf = *(const short8*)(kbase + (size_t)(j0 + lm) * NQK);
    f32x4 e0 = MFMA16(kf, qa0, z);
    f32x4 e1 = MFMA16(kf, qa1, z);
#pragma unroll
    for (int r = 0; r < 4; ++r) { s0 += EXP2(e0[r]); s1 += EXP2(e1[r]); }
  }
  s0 += __shfl_xor(s0, 16); s0 += __shfl_xor(s0, 32);
  s1 += __shfl_xor(s1, 16); s1 += __shfl_xor(s1, 32);
  if (lk == 0) { ldsd[lm][w] = s0; ldsd[16 + lm][w] = s1; }
  __syncthreads();

  // ---- roles for pass B ----
  int is = w & 1, jh = w >> 1;
  short8 qe = is ? qa1 : qa0;
  int prow = is * 16 + lm;                       // this lane's i-row (0..31)
  f32x4 d4 = *(const f32x4*)(&ldsd[prow][0]);
  float dinv = 1.0f / (d4[0] + d4[1] + d4[2] + d4[3]);

  float g = gamma[0];
  float* attn_b = attn + (size_t)b * NN * NN;
  float* aptr = attn_b + (size_t)(i0 + prow) * NN + jh * 32 + lk * 4;
  const unsigned short* vbb = vb + (size_t)b * NC * NN;
  // V staging: thread covers rows vrow+32s (s=0..7), 16B block vcol
  int vrow = t >> 3, vcol = t & 7;
  int voff = ((vcol * 16) ^ ((vrow & 7) << 4)) >> 1;  // pre-swizzled global elems
  char* vbase = (char*)ldsv;
  // P write cols (b64, XOR-swizzled; <=2-way)
  int psw = (prow & 7) << 4;
  int pc0 = (jh * 64 + lk * 8) ^ psw;
  int pc1 = (jh * 64 + lk * 8 + 32) ^ psw;
  // PV addressing
  int rowa = w * 64 + (l & 31);
  int sa = (rowa & 7) << 4;
  int sp = ((l & 31) & 7) << 4;
  int khalf = (l >> 5) * 16;
  const char* abase = vbase + rowa * 128;

  // V prologue: chunk 0 -> regs (pre-swizzled source)
  short8 vr[8];
#pragma unroll
  for (int s = 0; s < 8; ++s)
    vr[s] = *(const short8*)(vbb + (size_t)(vrow + 32 * s) * NN + voff);

  f32x16 acc0 = {}, acc1 = {};
  for (int tt = 0; tt < 64; ++tt) {
    int p = tt & 1;
    int jb = tt * 64 + jh * 32;
    // ---- energy + softmax + reg-direct attn store + P write ----
    short8 kf0 = *(const short8*)(kbase + (size_t)(jb + lm) * NQK);
    short8 kf1 = *(const short8*)(kbase + (size_t)(jb + 16 + lm) * NQK);
    f32x4 e0 = MFMA16(kf0, qe, z);
    f32x4 e1 = MFMA16(kf1, qe, z);
    f32x4 p0, p1;
#pragma unroll
    for (int r = 0; r < 4; ++r) {
      p0[r] = EXP2(e0[r]) * dinv;
      p1[r] = EXP2(e1[r]) * dinv;
    }
    __builtin_nontemporal_store(p0, (f32x4*)(aptr + tt * 64));
    __builtin_nontemporal_store(p1, (f32x4*)(aptr + tt * 64 + 16));
    short4v pb0, pb1;
#pragma unroll
    for (int r = 0; r < 4; ++r) {
      pb0[r] = (short)f2bf(p0[r]);
      pb1[r] = (short)f2bf(p1[r]);
    }
    char* pb = (char*)(&ldsp[p][0]) + prow * 128;
    *(short4v*)(pb + pc0) = pb0;
    *(short4v*)(pb + pc1) = pb1;
    __syncthreads();  // bar1: PV(tt-1) done (ldsv free), ldsp[p] complete
    // ---- V stage (linear LDS writes: conflict-free) + next-chunk loads ----
#pragma unroll
    for (int s = 0; s < 8; ++s)
      *(short8*)(vbase + (vrow + 32 * s) * 128 + vcol * 16) = vr[s];
    {
      size_t jn = (size_t)(((tt + 1) & 63) * 64);
#pragma unroll
      for (int s = 0; s < 8; ++s)
        vr[s] = *(const short8*)(vbb + (size_t)(vrow + 32 * s) * NN + jn + voff);
    }
    __syncthreads();  // bar2: ldsv ready
    // ---- PV: acc[c-slice][32 i] += V * P^T ----
    const char* pvp = (const char*)(&ldsp[p][0]) + (l & 31) * 128;
    __builtin_amdgcn_s_setprio(1);
#pragma unroll
    for (int kk = 0; kk < 4; ++kk) {
      int cb = kk * 32 + khalf;
      short8 af0 = *(const short8*)(abase + (cb ^ sa));
      short8 af1 = *(const short8*)(abase + 32 * 128 + (cb ^ sa));
      short8 pf = *(const short8*)(pvp + (cb ^ sp));
      acc0 = MFMA32(af0, pf, acc0);
      acc1 = MFMA32(af1, pf, acc1);
    }
    __builtin_amdgcn_s_setprio(0);
  }

  // ---- epilogue: out = gamma*O + x ----
  // 32x32 D map: col(i) = lane&31, row(c) = (reg&3) + 8*(reg>>2) + 4*(lane>>5)
  int ieg = i0 + (l & 31);
  int crb = w * 64 + 4 * (l >> 5);
#pragma unroll
  for (int reg = 0; reg < 16; ++reg) {
    int c = crb + (reg & 3) + 8 * (reg >> 2);
    size_t o0 = ((size_t)(b * NC + c)) * NN + ieg;
    size_t o1 = ((size_t)(b * NC + c + 32)) * NN + ieg;
    out[o0] = g * acc0[reg] + x[o0];
    out[o1] = g * acc1[reg] + x[o1];
  }
}

extern "C" void kernel_launch(void* const* d_in, const int* in_sizes, int n_in,
                              void* d_out, int out_size, void* d_ws, size_t ws_size,
                              hipStream_t stream) {
  (void)in_sizes; (void)n_in; (void)out_size; (void)ws_size;
  const float* x  = (const float*)d_in[0];
  const float* wq = (const float*)d_in[1];
  const float* bq = (const float*)d_in[2];
  const float* wk = (const float*)d_in[3];
  const float* bk = (const float*)d_in[4];
  const float* wv = (const float*)d_in[5];
  const float* bv = (const float*)d_in[6];
  const float* gamma = (const float*)d_in[7];
  float* out  = (float*)d_out;
  float* attn = out + (size_t)NB * NC * NN;

  char* ws = (char*)d_ws;
  unsigned short* qb  = (unsigned short*)(ws);               // 1,048,576 B
  unsigned short* kTb = (unsigned short*)(ws + 1048576);     // 1,048,576 B
  unsigned short* vb  = (unsigned short*)(ws + 2097152);     // 8,388,608 B
  unsigned short* wqb = (unsigned short*)(ws + 10485760);    //    16,384 B
  unsigned short* wkb = (unsigned short*)(ws + 10502144);    //    16,384 B
  unsigned short* wvb = (unsigned short*)(ws + 10518528);    //   131,072 B

  k_prep<<<dim3(256), dim3(256), 0, stream>>>(wq, wk, wv, wqb, wkb, wvb);
  k_proj<<<dim3(128, 4), dim3(256), 0, stream>>>(x, wqb, wkb, wvb, bq, bk, bv,
                                                 qb, kTb, vb);
  k_attn<<<dim3(512), dim3(256), 0, stream>>>(qb, kTb, vb, x, gamma, out, attn);
}